// Round 10
// baseline (278.916 us; speedup 1.0000x reference)
//
#include <hip/hip_runtime.h>
#include <hip/hip_bf16.h>

// q = x@Wq^T*scale; k = y@Wk^T; v = y@Wv^T
// out = strict_lower(q@k^T) @ v  -- causal LINEAR attention:
//   out_t = q_t @ P_t + strict_tril(q_t k_t^T) @ v_t,  P_t = sum_{c<t} k_c^T v_c
//
// v15 (from v13 @ 253.5us best; v14 tail-burst neutral -> reverted):
//  * gemm plateau (95us across 4 structures, all utils ~20%) attacked via
//    OCCUPANCY: BM 128->64. A-tile [64][64] fp32 = 16KB; LDS 48KB ->
//    3 blocks/CU (was 2); grid (128,8) = 1024 blocks (was 512). Per-wave
//    MFMA:staging ratio and global traffic unchanged; all frag/staging
//    patterns are the proven v10 ones (0 conflicts).
//  * out_gemm same split: 512 blocks (was 256 = 1/CU), 24KB LDS, BM=64.
//  * hs_gemm / prefix_scan / convert_w: v13-exact.
// ws (bf16 elems): q[4M] k[4M] kT[4M] vT[4M] | Ht[16M] Pt[16M]
//   wq(->Sd)/wk/wv[1M x3].

typedef __bf16 bf16x8 __attribute__((ext_vector_type(8)));
typedef __bf16 bf16x4 __attribute__((ext_vector_type(4)));
typedef __bf16 bf16x2 __attribute__((ext_vector_type(2)));
typedef float f32x4 __attribute__((ext_vector_type(4)));

#define MFMA16(a, b, c) __builtin_amdgcn_mfma_f32_16x16x32_bf16(a, b, c, 0, 0, 0)

constexpr float SCALE = 0.04419417382415922f; // 1/sqrt(512)

__device__ __forceinline__ void ld16(const void* g, void* l) {
    __builtin_amdgcn_global_load_lds(
        (__attribute__((address_space(1))) void*)g,
        (__attribute__((address_space(3))) void*)l, 16, 0, 0);
}

// bf16 tile frag: data-chunk c (16B) of row r, 128B rows (8 slots),
// slot = c ^ (r&7).
__device__ __forceinline__ bf16x8 frag(const __bf16* base, int r, int c) {
    return *(const bf16x8*)((const char*)base + r * 128 + ((c ^ (r & 7)) * 16));
}

// fp32 tile frag: chunks c0,c0+1 of row r, 256B rows (16 slots),
// slot = c ^ (r&15); cvt to bf16x8.
__device__ __forceinline__ bf16x8 fragA32(const float* base, int r, int c0) {
    const char* rowp = (const char*)base + r * 256;
    f32x4 a = *(const f32x4*)(rowp + ((c0 ^ (r & 15)) * 16));
    f32x4 b = *(const f32x4*)(rowp + (((c0 + 1) ^ (r & 15)) * 16));
    bf16x8 o;
    o[0] = (__bf16)a[0]; o[1] = (__bf16)a[1];
    o[2] = (__bf16)a[2]; o[3] = (__bf16)a[3];
    o[4] = (__bf16)b[0]; o[5] = (__bf16)b[1];
    o[6] = (__bf16)b[2]; o[7] = (__bf16)b[3];
    return o;
}

__device__ inline bf16x4 pack4(float4 a) {
    bf16x4 r;
    r[0] = (__bf16)a.x; r[1] = (__bf16)a.y;
    r[2] = (__bf16)a.z; r[3] = (__bf16)a.w;
    return r;
}

// ---------------------------------------------------------------------------
// Weights fp32 -> bf16 only. Wave owns 512 contiguous floats. 6144 waves.
// ---------------------------------------------------------------------------
__global__ __launch_bounds__(256) void convert_w(
    const float* __restrict__ wqf, const float* __restrict__ wkf,
    const float* __restrict__ wvf, __bf16* __restrict__ wqb,
    __bf16* __restrict__ wkb, __bf16* __restrict__ wvb)
{
    const size_t tid = (size_t)blockIdx.x * 256 + threadIdx.x;
    const size_t w = tid >> 6;
    const int lane = (int)(tid & 63);
    size_t f = w * 512;
    const float* src; __bf16* dst;
    if (f < 1048576)      { src = wqf; dst = wqb; }
    else if (f < 2097152) { src = wkf; dst = wkb; f -= 1048576; }
    else                  { src = wvf; dst = wvb; f -= 2097152; }
    const float4* s4 = (const float4*)(src + f);
    float4 a = s4[lane];
    float4 b = s4[64 + lane];
    __bf16* d = dst + f;
    *(bf16x4*)(d + lane * 4)       = pack4(a);
    *(bf16x4*)(d + 256 + lane * 4) = pack4(b);
}

// ---------------------------------------------------------------------------
// Fused q/kv GEMM, BM=64 / 3 blocks/CU. grid (128, 8): m0 = x*64,
// n0 = (y>>1)*128:
//   y even (q-block):  acc0 = bf16(x_t) @ Wq^T -> qo (SCALE folded)
//   y odd  (kv-block): acc0 = bf16(y_t) @ Wk^T -> ko + kT
//                      acc1 = bf16(y_t) @ Wv^T -> vT  (same staged A!)
// A staged raw fp32 async into [64][64] f32 (16-slot swizzle, c^(r&15));
// fp32->bf16 at frag-read. B staged bf16 (8-slot, v10-exact). 48KB LDS.
// Waves 2x2: wave covers rows (wave>>1)*32..+32, cols (wave&1)*64..+64.
// ---------------------------------------------------------------------------
__global__ __launch_bounds__(256, 3) void gemm_qkv2(
    const float* __restrict__ x, const float* __restrict__ y,
    const __bf16* __restrict__ wq, const __bf16* __restrict__ wk,
    const __bf16* __restrict__ wv, __bf16* __restrict__ qo,
    __bf16* __restrict__ ko, __bf16* __restrict__ kT,
    __bf16* __restrict__ vT)
{
    constexpr int K = 2048, N = 512;
    __shared__ __align__(16) float  Asf[64][64];      // 16 KB
    __shared__ __align__(16) __bf16 Bs[2][128][64];   // 32 KB

    const bool iskv = (blockIdx.y & 1) != 0;
    const float* A = iskv ? y : x;
    const __bf16* B0 = iskv ? wk : wq;

    const int tid  = threadIdx.x;
    const int wave = tid >> 6, lane = tid & 63;
    const int fr = lane & 15, fq = lane >> 4;
    const int m0 = blockIdx.x * 64, n0 = (blockIdx.y >> 1) * 128;
    const int wr = (wave >> 1) * 32, wc = (wave & 1) * 64;
    const int lr = lane >> 3;            // B staging: row within 8-row group
    const int cd = (lane & 7) ^ lr;      // B staging: swizzled source chunk
    // A staging: issue u covers rows u*16 + wave*4 + (lane>>4); slot lane&15;
    // (row&15) == wave*4 + (lane>>4) == ar -> source chunk invariant.
    const int ar  = wave * 4 + (lane >> 4);
    const int ac  = (lane & 15) ^ ar;

    f32x4 acc0[2][4], acc1[2][4];
#pragma unroll
    for (int a = 0; a < 2; ++a)
#pragma unroll
        for (int b = 0; b < 4; ++b) {
            acc0[a][b] = f32x4{0.f, 0.f, 0.f, 0.f};
            acc1[a][b] = f32x4{0.f, 0.f, 0.f, 0.f};
        }

    const __bf16* bg0 = B0 + (size_t)(n0 + wave * 32 + lr) * K + cd * 8;
    const __bf16* bg1 = wv + (size_t)(n0 + wave * 32 + lr) * K + cd * 8;
    __bf16* bl0 = &Bs[0][wave * 32][0];
    __bf16* bl1 = &Bs[1][wave * 32][0];
    float*  alf = &Asf[0][0] + wave * 256 + lane * 4;   // + u*1024 per issue
    const float* ag0 = A + (size_t)(m0 + ar) * K + ac * 4;  // + u*16 rows

    for (int kk = 0; kk < K; kk += 64) {
        __syncthreads();                 // prev step's frag reads done
#pragma unroll
        for (int u = 0; u < 4; ++u)
            ld16(bg0 + (size_t)(u * 8) * K + kk, bl0 + u * 512);
        if (iskv) {
#pragma unroll
            for (int u = 0; u < 4; ++u)
                ld16(bg1 + (size_t)(u * 8) * K + kk, bl1 + u * 512);
        }
#pragma unroll
        for (int u = 0; u < 4; ++u)
            ld16(ag0 + (size_t)(u * 16) * K + kk, alf + u * 1024);
        __syncthreads();                 // drains vmcnt: tiles visible
#pragma unroll
        for (int ks = 0; ks < 2; ++ks) {
            bf16x8 af[2], bf[4];
#pragma unroll
            for (int rt = 0; rt < 2; ++rt)
                af[rt] = fragA32(&Asf[0][0], wr + rt * 16 + fr, ks * 8 + fq * 2);
#pragma unroll
            for (int nt = 0; nt < 4; ++nt)
                bf[nt] = frag(&Bs[0][0][0], wc + nt * 16 + fr, ks * 4 + fq);
#pragma unroll
            for (int rt = 0; rt < 2; ++rt)
#pragma unroll
                for (int nt = 0; nt < 4; ++nt)
                    acc0[rt][nt] = MFMA16(af[rt], bf[nt], acc0[rt][nt]);
            if (iskv) {
                bf16x8 bg[4];
#pragma unroll
                for (int nt = 0; nt < 4; ++nt)
                    bg[nt] = frag(&Bs[1][0][0], wc + nt * 16 + fr, ks * 4 + fq);
#pragma unroll
                for (int rt = 0; rt < 2; ++rt)
#pragma unroll
                    for (int nt = 0; nt < 4; ++nt)
                        acc1[rt][nt] = MFMA16(af[rt], bg[nt], acc1[rt][nt]);
            }
        }
    }

    if (!iskv) {
#pragma unroll
        for (int rt = 0; rt < 2; ++rt)
#pragma unroll
            for (int nt = 0; nt < 4; ++nt) {
                const int col = n0 + wc + nt * 16 + fr;
#pragma unroll
                for (int r = 0; r < 4; ++r) {
                    const int row = m0 + wr + rt * 16 + fq * 4 + r;
                    qo[(size_t)row * N + col] = (__bf16)(acc0[rt][nt][r] * SCALE);
                }
            }
    } else {
#pragma unroll
        for (int rt = 0; rt < 2; ++rt)
#pragma unroll
            for (int nt = 0; nt < 4; ++nt) {
                const int col  = n0 + wc + nt * 16 + fr;
                const int row0 = m0 + wr + rt * 16 + fq * 4;
                bf16x4 k4, v4;
#pragma unroll
                for (int r = 0; r < 4; ++r) {
                    k4[r] = (__bf16)acc0[rt][nt][r];
                    v4[r] = (__bf16)acc1[rt][nt][r];
                    ko[(size_t)(row0 + r) * N + col] = k4[r];
                }
                *(bf16x4*)(kT + (size_t)col * 8192 + row0) = k4;
                *(bf16x4*)(vT + (size_t)col * 8192 + row0) = v4;
            }
    }
}

// ---------------------------------------------------------------------------
// Merged H + diagonal-S launch (v13-exact), grid (16, 67):
//  y <  63: Ht[c][n][d] = (vT_c @ kT_c^T), c = y, K=128
//  y >= 63: Sd[t] = strict_tril(q_t @ k_t^T), t = (y-63)*16 + x, K=512
// ---------------------------------------------------------------------------
__global__ __launch_bounds__(256, 3) void hs_gemm(
    const __bf16* __restrict__ vT, const __bf16* __restrict__ kT,
    const __bf16* __restrict__ q, const __bf16* __restrict__ k,
    __bf16* __restrict__ Ht, __bf16* __restrict__ Sd)
{
    __shared__ __align__(16) __bf16 As[128][64];
    __shared__ __align__(16) __bf16 Bs[128][64];

    const int tid  = threadIdx.x;
    const int wave = tid >> 6, lane = tid & 63;
    const int fr = lane & 15, fq = lane >> 4;
    const int wr = (wave >> 1) * 64, wc = (wave & 1) * 64;
    const int lr = lane >> 3;
    const int cd = (lane & 7) ^ lr;

    f32x4 acc[4][4];
#pragma unroll
    for (int a = 0; a < 4; ++a)
#pragma unroll
        for (int b = 0; b < 4; ++b) acc[a][b] = f32x4{0.f, 0.f, 0.f, 0.f};

    __bf16* al = &As[wave * 32][0];
    __bf16* bl = &Bs[wave * 32][0];

    if (blockIdx.y < 63) {
        const int c  = blockIdx.y;
        const int m0 = (blockIdx.x & 3) * 128;
        const int n0 = (blockIdx.x >> 2) * 128;

        const __bf16* ag = vT + (size_t)(m0 + wave * 32 + lr) * 8192 + c * 128 + cd * 8;
        const __bf16* bg = kT + (size_t)(n0 + wave * 32 + lr) * 8192 + c * 128 + cd * 8;

        for (int kk = 0; kk < 128; kk += 64) {
            __syncthreads();
#pragma unroll
            for (int u = 0; u < 4; ++u) {
                ld16(ag + (size_t)(u * 8) * 8192 + kk, al + u * 512);
                ld16(bg + (size_t)(u * 8) * 8192 + kk, bl + u * 512);
            }
            __syncthreads();
#pragma unroll
            for (int ks = 0; ks < 2; ++ks) {
                bf16x8 af[4], bf[4];
#pragma unroll
                for (int rt = 0; rt < 4; ++rt)
                    af[rt] = frag(&As[0][0], wr + rt * 16 + fr, ks * 4 + fq);
#pragma unroll
                for (int nt = 0; nt < 4; ++nt)
                    bf[nt] = frag(&Bs[0][0], wc + nt * 16 + fr, ks * 4 + fq);
#pragma unroll
                for (int rt = 0; rt < 4; ++rt)
#pragma unroll
                    for (int nt = 0; nt < 4; ++nt)
                        acc[rt][nt] = MFMA16(af[rt], bf[nt], acc[rt][nt]);
            }
        }

        __bf16* tp = Ht + (size_t)c * 262144;
#pragma unroll
        for (int rt = 0; rt < 4; ++rt)
#pragma unroll
            for (int nt = 0; nt < 4; ++nt) {
                const int col = n0 + wc + nt * 16 + fr;
#pragma unroll
                for (int r = 0; r < 4; ++r) {
                    const int row = m0 + wr + rt * 16 + fq * 4 + r;
                    tp[(size_t)row * 512 + col] = (__bf16)acc[rt][nt][r];
                }
            }
    } else {
        const int t = (blockIdx.y - 63) * 16 + blockIdx.x;

        const __bf16* ag = q + (size_t)(t * 128 + wave * 32 + lr) * 512 + cd * 8;
        const __bf16* bg = k + (size_t)(t * 128 + wave * 32 + lr) * 512 + cd * 8;

        for (int kk = 0; kk < 512; kk += 64) {
            __syncthreads();
#pragma unroll
            for (int u = 0; u < 4; ++u) {
                ld16(ag + (size_t)(u * 8) * 512 + kk, al + u * 512);
                ld16(bg + (size_t)(u * 8) * 512 + kk, bl + u * 512);
            }
            __syncthreads();
#pragma unroll
            for (int ks = 0; ks < 2; ++ks) {
                bf16x8 af[4], bf[4];
#pragma unroll
                for (int rt = 0; rt < 4; ++rt)
                    af[rt] = frag(&As[0][0], wr + rt * 16 + fr, ks * 4 + fq);
#pragma unroll
                for (int nt = 0; nt < 4; ++nt)
                    bf[nt] = frag(&Bs[0][0], wc + nt * 16 + fr, ks * 4 + fq);
#pragma unroll
                for (int rt = 0; rt < 4; ++rt)
#pragma unroll
                    for (int nt = 0; nt < 4; ++nt)
                        acc[rt][nt] = MFMA16(af[rt], bf[nt], acc[rt][nt]);
            }
        }

        __bf16* tp = Sd + (size_t)t * 16384;
#pragma unroll
        for (int rt = 0; rt < 4; ++rt)
#pragma unroll
            for (int nt = 0; nt < 4; ++nt) {
                const int col = wc + nt * 16 + fr;
#pragma unroll
                for (int r = 0; r < 4; ++r) {
                    const int row = wr + rt * 16 + fq * 4 + r;
                    float vv = (col < row) ? acc[rt][nt][r] : 0.f;
                    tp[row * 128 + col] = (__bf16)vv;
                }
            }
    }
}

// ---------------------------------------------------------------------------
// Exclusive prefix over chunk axis: Pt[c] = sum_{c'<c} Ht[c'], fp32 accum.
// 512 blocks x 256 thr, 2 elems/thread (v13-exact).
// ---------------------------------------------------------------------------
__global__ __launch_bounds__(256) void prefix_scan(
    const __bf16* __restrict__ Ht, __bf16* __restrict__ Pt)
{
    const size_t e = ((size_t)blockIdx.x * 256 + threadIdx.x) * 2;
    float a0 = 0.f, a1 = 0.f;
#pragma unroll 9
    for (int c = 0; c < 63; ++c) {
        bf16x2 h = *(const bf16x2*)(Ht + (size_t)c * 262144 + e);
        a0 += (float)h[0]; a1 += (float)h[1];
        bf16x2 p;
        p[0] = (__bf16)a0; p[1] = (__bf16)a1;
        *(bf16x2*)(Pt + (size_t)(c + 1) * 262144 + e) = p;
    }
}

// ---------------------------------------------------------------------------
// Out kernel, BM=64 split. grid (128, 4): th = bx -> t = th>>1, h = th&1;
// block owns out rows t*128 + h*64 .. +64, cols n0..n0+128.
//   rounds 0..7 (t>0): acc += q-rows @ Pt_t slice (K=512)
//   last 2 rounds:     acc += Sd[t] rows h*64.. @ v_t slice (K=128)
// A [64][64] bf16 8KB + B [128][64] 16KB = 24KB LDS; 512 blocks = 2/CU.
// ---------------------------------------------------------------------------
__global__ __launch_bounds__(256, 2) void out_gemm(
    const __bf16* __restrict__ q, const __bf16* __restrict__ Sd,
    const __bf16* __restrict__ vT, const __bf16* __restrict__ Pt,
    float* __restrict__ out)
{
    __shared__ __align__(16) __bf16 As[64][64];     // 8 KB
    __shared__ __align__(16) __bf16 Bs[128][64];    // 16 KB

    const int th = blockIdx.x;
    const int t = th >> 1, h = th & 1;
    const int r0 = t * 128 + h * 64;
    const int n0 = blockIdx.y * 128;

    const int tid  = threadIdx.x;
    const int wave = tid >> 6, lane = tid & 63;
    const int fr = lane & 15, fq = lane >> 4;
    const int wr = (wave >> 1) * 32, wc = (wave & 1) * 64;
    const int lr = lane >> 3;
    const int cd = (lane & 7) ^ lr;          // B staging chunk
    // A staging: issue u covers row u*32 + wave*8 + (lane>>3); slot lane&7
    const int ar8 = wave * 8 + (lane >> 3);  // 0..31, == row&31 (u*32 even)
    const int acA = (lane & 7) ^ (ar8 & 7);  // source chunk, loop-invariant

    f32x4 acc[2][4];
#pragma unroll
    for (int a = 0; a < 2; ++a)
#pragma unroll
        for (int b = 0; b < 4; ++b) acc[a][b] = f32x4{0.f, 0.f, 0.f, 0.f};

    const __bf16* qB  = q  + (size_t)r0 * 512;
    const __bf16* ptB = Pt + (size_t)t * 262144 + (size_t)n0 * 512;
    const __bf16* sdB = Sd + (size_t)t * 16384 + (size_t)(h * 64) * 128;
    const __bf16* vtB = vT + (size_t)n0 * 8192 + t * 128;

    const int ns = (t > 0) ? 10 : 2;

    for (int s = 0; s < ns; ++s) {
        const __bf16 *ap, *bp; size_t sa, sb;
        if (t > 0 && s < 8) { ap = qB + s * 64;  sa = 512;  bp = ptB + s * 64; sb = 512; }
        else { const int sc = (t > 0) ? s - 8 : s;
               ap = sdB + sc * 64; sa = 128; bp = vtB + sc * 64; sb = 8192; }
        __syncthreads();                 // prev round's frag reads done
#pragma unroll
        for (int u = 0; u < 2; ++u)      // A: [64][64] bf16, 2 issues/lane
            ld16(ap + (size_t)(u * 32 + ar8) * sa + acA * 8,
                 &As[0][0] + wave * 512 + u * 2048 + lane * 8);
#pragma unroll
        for (int u = 0; u < 4; ++u)      // B: [128][64] bf16, 4 issues/lane
            ld16(bp + (size_t)(wave * 32 + u * 8 + lr) * sb + cd * 8,
                 &Bs[wave * 32][0] + u * 512);
        __syncthreads();                 // burst drained
#pragma unroll
        for (int ks = 0; ks < 2; ++ks) {
            bf16x8 af[2], bf[4];
#pragma unroll
            for (int rt = 0; rt < 2; ++rt)
                af[rt] = frag(&As[0][0], wr + rt * 16 + fr, ks * 4 + fq);
#pragma unroll
            for (int nt = 0; nt < 4; ++nt)
                bf[nt] = frag(&Bs[0][0], wc + nt * 16 + fr, ks * 4 + fq);
#pragma unroll
            for (int rt = 0; rt < 2; ++rt)
#pragma unroll
                for (int nt = 0; nt < 4; ++nt)
                    acc[rt][nt] = MFMA16(af[rt], bf[nt], acc[rt][nt]);
        }
    }

    // epilogue: exclusive owner of this 64x128 tile -> plain fp32 store
#pragma unroll
    for (int rt = 0; rt < 2; ++rt)
#pragma unroll
        for (int nt = 0; nt < 4; ++nt) {
            const int col = n0 + wc + nt * 16 + fr;
#pragma unroll
            for (int r = 0; r < 4; ++r) {
                const int row = r0 + wr + rt * 16 + fq * 4 + r;
                out[(size_t)row * 512 + col] = acc[rt][nt][r];
            }
        }
}

// ---------------------------------------------------------------------------
extern "C" void kernel_launch(void* const* d_in, const int* in_sizes, int n_in,
                              void* d_out, int out_size, void* d_ws, size_t ws_size,
                              hipStream_t stream) {
    const float* x  = (const float*)d_in[0];
    const float* y  = (const float*)d_in[1];
    const float* Wq = (const float*)d_in[2];
    const float* Wk = (const float*)d_in[3];
    const float* Wv = (const float*)d_in[4];
    float* out = (float*)d_out;

    const size_t QK = (size_t)8192 * 512;       // 4194304
    __bf16* q  = (__bf16*)d_ws;
    __bf16* k  = q + QK;
    __bf16* kT = k + QK;
    __bf16* vT = kT + QK;
    __bf16* Ht  = vT + QK;                      // 16777216-elem region
    __bf16* Pt  = Ht + 16777216;                // 16777216-elem region
    __bf16* wqb = Pt + 16777216;
    __bf16* wkb = wqb + 1048576;
    __bf16* wvb = wkb + 1048576;
    __bf16* Sd = wqb;                           // alias: wqb dead after gemm

    convert_w<<<1536, 256, 0, stream>>>(Wq, Wk, Wv, wqb, wkb, wvb);
    gemm_qkv2<<<dim3(128, 8), 256, 0, stream>>>(x, y, wqb, wkb, wvb, q, k, kT, vT);
    hs_gemm<<<dim3(16, 67), 256, 0, stream>>>(vT, kT, q, k, Ht, Sd);
    prefix_scan<<<512, 256, 0, stream>>>(Ht, Pt);
    out_gemm<<<dim3(128, 4), 256, 0, stream>>>(q, Sd, vT, Pt, out);
}

// Round 11
// 250.958 us; speedup vs baseline: 1.1114x; 1.1114x over previous
//
#include <hip/hip_runtime.h>
#include <hip/hip_bf16.h>

// q = x@Wq^T*scale; k = y@Wk^T; v = y@Wv^T
// out = strict_lower(q@k^T) @ v  -- causal LINEAR attention:
//   out_t = q_t @ P_t + strict_tril(q_t k_t^T) @ v_t,  P_t = sum_{c<t} k_c^T v_c
//
// v16 (from v15 @ 278.9us regression; best = v13 @ 253.5us):
//  * v15 post-mortem: BM=64 doubled HBM FETCH (91->200MB) -- 1024 blocks >
//    768 resident broke L3 temporal locality. REVERTED to v13 everywhere.
//  * Single change: XCD-aware block swizzle in gemm_qkv2 (T1). Blocks
//    sharing an A-slice (same m0, 4 n/kv configs) now co-reside on ONE XCD:
//    lin=by*64+bx; xcd=lin&7; idx=lin>>3; m=xcd*8+(idx&7); ycfg=idx>>3.
//    Per-K-step XCD working set ~0.7MB << 4MB L2 -> A staged from L2 not L3.
// ws (bf16 elems): q[4M] k[4M] kT[4M] vT[4M] | Ht[16M] Pt[16M]
//   wq(->Sd)/wk/wv[1M x3].

typedef __bf16 bf16x8 __attribute__((ext_vector_type(8)));
typedef __bf16 bf16x4 __attribute__((ext_vector_type(4)));
typedef __bf16 bf16x2 __attribute__((ext_vector_type(2)));
typedef float f32x4 __attribute__((ext_vector_type(4)));

#define MFMA16(a, b, c) __builtin_amdgcn_mfma_f32_16x16x32_bf16(a, b, c, 0, 0, 0)

constexpr float SCALE = 0.04419417382415922f; // 1/sqrt(512)

__device__ __forceinline__ void ld16(const void* g, void* l) {
    __builtin_amdgcn_global_load_lds(
        (__attribute__((address_space(1))) void*)g,
        (__attribute__((address_space(3))) void*)l, 16, 0, 0);
}

// bf16 tile frag: data-chunk c (16B) of row r from [128][64] bf16 tile
// (128B rows, 8 slots), slot = c ^ (r&7).
__device__ __forceinline__ bf16x8 frag(const __bf16* base, int r, int c) {
    return *(const bf16x8*)((const char*)base + r * 128 + ((c ^ (r & 7)) * 16));
}

// fp32 tile frag: chunks c0,c0+1 (16B each = 4 floats) of row r from
// [128][64] fp32 tile (256B rows, 16 slots), slot = c ^ (r&15); cvt to bf16x8.
__device__ __forceinline__ bf16x8 fragA32(const float* base, int r, int c0) {
    const char* rowp = (const char*)base + r * 256;
    f32x4 a = *(const f32x4*)(rowp + ((c0 ^ (r & 15)) * 16));
    f32x4 b = *(const f32x4*)(rowp + (((c0 + 1) ^ (r & 15)) * 16));
    bf16x8 o;
    o[0] = (__bf16)a[0]; o[1] = (__bf16)a[1];
    o[2] = (__bf16)a[2]; o[3] = (__bf16)a[3];
    o[4] = (__bf16)b[0]; o[5] = (__bf16)b[1];
    o[6] = (__bf16)b[2]; o[7] = (__bf16)b[3];
    return o;
}

__device__ inline bf16x4 pack4(float4 a) {
    bf16x4 r;
    r[0] = (__bf16)a.x; r[1] = (__bf16)a.y;
    r[2] = (__bf16)a.z; r[3] = (__bf16)a.w;
    return r;
}

// ---------------------------------------------------------------------------
// Weights fp32 -> bf16 only. Wave owns 512 contiguous floats. 6144 waves.
// ---------------------------------------------------------------------------
__global__ __launch_bounds__(256) void convert_w(
    const float* __restrict__ wqf, const float* __restrict__ wkf,
    const float* __restrict__ wvf, __bf16* __restrict__ wqb,
    __bf16* __restrict__ wkb, __bf16* __restrict__ wvb)
{
    const size_t tid = (size_t)blockIdx.x * 256 + threadIdx.x;
    const size_t w = tid >> 6;
    const int lane = (int)(tid & 63);
    size_t f = w * 512;
    const float* src; __bf16* dst;
    if (f < 1048576)      { src = wqf; dst = wqb; }
    else if (f < 2097152) { src = wkf; dst = wkb; f -= 1048576; }
    else                  { src = wvf; dst = wvb; f -= 2097152; }
    const float4* s4 = (const float4*)(src + f);
    float4 a = s4[lane];
    float4 b = s4[64 + lane];
    __bf16* d = dst + f;
    *(bf16x4*)(d + lane * 4)       = pack4(a);
    *(bf16x4*)(d + 256 + lane * 4) = pack4(b);
}

// ---------------------------------------------------------------------------
// Fused q/kv GEMM (v13 structure + XCD swizzle). 512 blocks:
//   ycfg even (q-block):  acc0 = bf16(x_t) @ Wq^T -> qo (SCALE folded)
//   ycfg odd  (kv-block): acc0 = bf16(y_t) @ Wk^T -> ko + kT
//                         acc1 = bf16(y_t) @ Wv^T -> vT  (same staged A!)
// XCD swizzle: lin%8 = XCD owns m-tiles [xcd*8, xcd*8+8) for all 8 ycfgs,
// so the 4 blocks sharing each A-slice are co-resident on one XCD's L2.
// A staged raw fp32 async into [128][64] f32 (16-slot swizzle, c^(r&15));
// fp32->bf16 at frag-read. B staged bf16 (8-slot). 64KB LDS, 2 blocks/CU.
// ---------------------------------------------------------------------------
__global__ __launch_bounds__(256, 2) void gemm_qkv2(
    const float* __restrict__ x, const float* __restrict__ y,
    const __bf16* __restrict__ wq, const __bf16* __restrict__ wk,
    const __bf16* __restrict__ wv, __bf16* __restrict__ qo,
    __bf16* __restrict__ ko, __bf16* __restrict__ kT,
    __bf16* __restrict__ vT)
{
    constexpr int K = 2048, N = 512;
    __shared__ __align__(16) float  Asf[128][64];     // 32 KB
    __shared__ __align__(16) __bf16 Bs[2][128][64];   // 32 KB

    // XCD-aware remap (bijective on 512 blocks; lin%8 assumed = XCD)
    const int lin  = blockIdx.y * 64 + blockIdx.x;
    const int xcd  = lin & 7;
    const int idx  = lin >> 3;
    const int mb   = xcd * 8 + (idx & 7);   // m-tile 0..63
    const int ycfg = idx >> 3;              // 0..7

    const bool iskv = (ycfg & 1) != 0;
    const float* A = iskv ? y : x;
    const __bf16* B0 = iskv ? wk : wq;

    const int tid  = threadIdx.x;
    const int wave = tid >> 6, lane = tid & 63;
    const int fr = lane & 15, fq = lane >> 4;
    const int m0 = mb * 128, n0 = (ycfg >> 1) * 128;
    const int wr = (wave >> 1) * 64, wc = (wave & 1) * 64;
    const int lr = lane >> 3;            // B staging: row within 8-row group
    const int cd = (lane & 7) ^ lr;      // B staging: swizzled chunk
    const int lr4 = lane >> 4;           // A staging: row within 4-row group
    const int cl  = lane & 15;           // A staging: LDS slot (16 per row)

    f32x4 acc0[4][4], acc1[4][4];
#pragma unroll
    for (int a = 0; a < 4; ++a)
#pragma unroll
        for (int b = 0; b < 4; ++b) {
            acc0[a][b] = f32x4{0.f, 0.f, 0.f, 0.f};
            acc1[a][b] = f32x4{0.f, 0.f, 0.f, 0.f};
        }

    const __bf16* bg0 = B0 + (size_t)(n0 + wave * 32 + lr) * K + cd * 8;
    const __bf16* bg1 = wv + (size_t)(n0 + wave * 32 + lr) * K + cd * 8;
    float*  alf = &Asf[wave * 32][0];
    __bf16* bl0 = &Bs[0][wave * 32][0];
    __bf16* bl1 = &Bs[1][wave * 32][0];
    const float* ag0 = A + (size_t)(m0 + wave * 32 + lr4) * K;

    for (int kk = 0; kk < K; kk += 64) {
        __syncthreads();                 // prev step's frag reads done
#pragma unroll
        for (int u = 0; u < 4; ++u)
            ld16(bg0 + (size_t)(u * 8) * K + kk, bl0 + u * 512);
        if (iskv) {
#pragma unroll
            for (int u = 0; u < 4; ++u)
                ld16(bg1 + (size_t)(u * 8) * K + kk, bl1 + u * 512);
        }
#pragma unroll
        for (int u = 0; u < 8; ++u) {
            const int rw = u * 4 + lr4;          // row within wave group
            const int c  = cl ^ (rw & 15);       // source data chunk
            ld16(ag0 + (size_t)(u * 4) * K + kk + c * 4, alf + u * 256);
        }
        __syncthreads();                 // drains vmcnt: tiles visible
#pragma unroll
        for (int ks = 0; ks < 2; ++ks) {
            bf16x8 af[4], bf[4];
#pragma unroll
            for (int rt = 0; rt < 4; ++rt)
                af[rt] = fragA32(&Asf[0][0], wr + rt * 16 + fr, ks * 8 + fq * 2);
#pragma unroll
            for (int nt = 0; nt < 4; ++nt)
                bf[nt] = frag(&Bs[0][0][0], wc + nt * 16 + fr, ks * 4 + fq);
#pragma unroll
            for (int rt = 0; rt < 4; ++rt)
#pragma unroll
                for (int nt = 0; nt < 4; ++nt)
                    acc0[rt][nt] = MFMA16(af[rt], bf[nt], acc0[rt][nt]);
            if (iskv) {
                bf16x8 bg[4];
#pragma unroll
                for (int nt = 0; nt < 4; ++nt)
                    bg[nt] = frag(&Bs[1][0][0], wc + nt * 16 + fr, ks * 4 + fq);
#pragma unroll
                for (int rt = 0; rt < 4; ++rt)
#pragma unroll
                    for (int nt = 0; nt < 4; ++nt)
                        acc1[rt][nt] = MFMA16(af[rt], bg[nt], acc1[rt][nt]);
            }
        }
    }

    if (!iskv) {
#pragma unroll
        for (int rt = 0; rt < 4; ++rt)
#pragma unroll
            for (int nt = 0; nt < 4; ++nt) {
                const int col = n0 + wc + nt * 16 + fr;
#pragma unroll
                for (int r = 0; r < 4; ++r) {
                    const int row = m0 + wr + rt * 16 + fq * 4 + r;
                    qo[(size_t)row * N + col] = (__bf16)(acc0[rt][nt][r] * SCALE);
                }
            }
    } else {
#pragma unroll
        for (int rt = 0; rt < 4; ++rt)
#pragma unroll
            for (int nt = 0; nt < 4; ++nt) {
                const int col  = n0 + wc + nt * 16 + fr;
                const int row0 = m0 + wr + rt * 16 + fq * 4;
                bf16x4 k4, v4;
#pragma unroll
                for (int r = 0; r < 4; ++r) {
                    k4[r] = (__bf16)acc0[rt][nt][r];
                    v4[r] = (__bf16)acc1[rt][nt][r];
                    ko[(size_t)(row0 + r) * N + col] = k4[r];
                }
                *(bf16x4*)(kT + (size_t)col * 8192 + row0) = k4;
                *(bf16x4*)(vT + (size_t)col * 8192 + row0) = v4;
            }
    }
}

// ---------------------------------------------------------------------------
// Merged H + diagonal-S launch (v13-exact), grid (16, 67):
//  y <  63: Ht[c][n][d] = (vT_c @ kT_c^T), c = y, K=128
//  y >= 63: Sd[t] = strict_tril(q_t @ k_t^T), t = (y-63)*16 + x, K=512
// ---------------------------------------------------------------------------
__global__ __launch_bounds__(256, 3) void hs_gemm(
    const __bf16* __restrict__ vT, const __bf16* __restrict__ kT,
    const __bf16* __restrict__ q, const __bf16* __restrict__ k,
    __bf16* __restrict__ Ht, __bf16* __restrict__ Sd)
{
    __shared__ __align__(16) __bf16 As[128][64];
    __shared__ __align__(16) __bf16 Bs[128][64];

    const int tid  = threadIdx.x;
    const int wave = tid >> 6, lane = tid & 63;
    const int fr = lane & 15, fq = lane >> 4;
    const int wr = (wave >> 1) * 64, wc = (wave & 1) * 64;
    const int lr = lane >> 3;
    const int cd = (lane & 7) ^ lr;

    f32x4 acc[4][4];
#pragma unroll
    for (int a = 0; a < 4; ++a)
#pragma unroll
        for (int b = 0; b < 4; ++b) acc[a][b] = f32x4{0.f, 0.f, 0.f, 0.f};

    __bf16* al = &As[wave * 32][0];
    __bf16* bl = &Bs[wave * 32][0];

    if (blockIdx.y < 63) {
        const int c  = blockIdx.y;
        const int m0 = (blockIdx.x & 3) * 128;
        const int n0 = (blockIdx.x >> 2) * 128;

        const __bf16* ag = vT + (size_t)(m0 + wave * 32 + lr) * 8192 + c * 128 + cd * 8;
        const __bf16* bg = kT + (size_t)(n0 + wave * 32 + lr) * 8192 + c * 128 + cd * 8;

        for (int kk = 0; kk < 128; kk += 64) {
            __syncthreads();
#pragma unroll
            for (int u = 0; u < 4; ++u) {
                ld16(ag + (size_t)(u * 8) * 8192 + kk, al + u * 512);
                ld16(bg + (size_t)(u * 8) * 8192 + kk, bl + u * 512);
            }
            __syncthreads();
#pragma unroll
            for (int ks = 0; ks < 2; ++ks) {
                bf16x8 af[4], bf[4];
#pragma unroll
                for (int rt = 0; rt < 4; ++rt)
                    af[rt] = frag(&As[0][0], wr + rt * 16 + fr, ks * 4 + fq);
#pragma unroll
                for (int nt = 0; nt < 4; ++nt)
                    bf[nt] = frag(&Bs[0][0], wc + nt * 16 + fr, ks * 4 + fq);
#pragma unroll
                for (int rt = 0; rt < 4; ++rt)
#pragma unroll
                    for (int nt = 0; nt < 4; ++nt)
                        acc[rt][nt] = MFMA16(af[rt], bf[nt], acc[rt][nt]);
            }
        }

        __bf16* tp = Ht + (size_t)c * 262144;
#pragma unroll
        for (int rt = 0; rt < 4; ++rt)
#pragma unroll
            for (int nt = 0; nt < 4; ++nt) {
                const int col = n0 + wc + nt * 16 + fr;
#pragma unroll
                for (int r = 0; r < 4; ++r) {
                    const int row = m0 + wr + rt * 16 + fq * 4 + r;
                    tp[(size_t)row * 512 + col] = (__bf16)acc[rt][nt][r];
                }
            }
    } else {
        const int t = (blockIdx.y - 63) * 16 + blockIdx.x;

        const __bf16* ag = q + (size_t)(t * 128 + wave * 32 + lr) * 512 + cd * 8;
        const __bf16* bg = k + (size_t)(t * 128 + wave * 32 + lr) * 512 + cd * 8;

        for (int kk = 0; kk < 512; kk += 64) {
            __syncthreads();
#pragma unroll
            for (int u = 0; u < 4; ++u) {
                ld16(ag + (size_t)(u * 8) * 512 + kk, al + u * 512);
                ld16(bg + (size_t)(u * 8) * 512 + kk, bl + u * 512);
            }
            __syncthreads();
#pragma unroll
            for (int ks = 0; ks < 2; ++ks) {
                bf16x8 af[4], bf[4];
#pragma unroll
                for (int rt = 0; rt < 4; ++rt)
                    af[rt] = frag(&As[0][0], wr + rt * 16 + fr, ks * 4 + fq);
#pragma unroll
                for (int nt = 0; nt < 4; ++nt)
                    bf[nt] = frag(&Bs[0][0], wc + nt * 16 + fr, ks * 4 + fq);
#pragma unroll
                for (int rt = 0; rt < 4; ++rt)
#pragma unroll
                    for (int nt = 0; nt < 4; ++nt)
                        acc[rt][nt] = MFMA16(af[rt], bf[nt], acc[rt][nt]);
            }
        }

        __bf16* tp = Sd + (size_t)t * 16384;
#pragma unroll
        for (int rt = 0; rt < 4; ++rt)
#pragma unroll
            for (int nt = 0; nt < 4; ++nt) {
                const int col = wc + nt * 16 + fr;
#pragma unroll
                for (int r = 0; r < 4; ++r) {
                    const int row = wr + rt * 16 + fq * 4 + r;
                    float vv = (col < row) ? acc[rt][nt][r] : 0.f;
                    tp[row * 128 + col] = (__bf16)vv;
                }
            }
    }
}

// ---------------------------------------------------------------------------
// Exclusive prefix over chunk axis: Pt[c] = sum_{c'<c} Ht[c'], fp32 accum.
// 512 blocks x 256 thr, 2 elems/thread (v13-exact).
// ---------------------------------------------------------------------------
__global__ __launch_bounds__(256) void prefix_scan(
    const __bf16* __restrict__ Ht, __bf16* __restrict__ Pt)
{
    const size_t e = ((size_t)blockIdx.x * 256 + threadIdx.x) * 2;
    float a0 = 0.f, a1 = 0.f;
#pragma unroll 9
    for (int c = 0; c < 63; ++c) {
        bf16x2 h = *(const bf16x2*)(Ht + (size_t)c * 262144 + e);
        a0 += (float)h[0]; a1 += (float)h[1];
        bf16x2 p;
        p[0] = (__bf16)a0; p[1] = (__bf16)a1;
        *(bf16x2*)(Pt + (size_t)(c + 1) * 262144 + e) = p;
    }
}

// ---------------------------------------------------------------------------
// Out kernel (v13-exact), block (t, n0):
// Phase B: acc = q_t @ Pt_t (K=512, skipped for t=0)
// Phase C: acc += Sd[t] @ v_t (K=128, both operands staged via ld16)
// Non-atomic fp32 store (block owns its 128x128 tile).
// ---------------------------------------------------------------------------
__global__ __launch_bounds__(256, 3) void out_gemm(
    const __bf16* __restrict__ q, const __bf16* __restrict__ Sd,
    const __bf16* __restrict__ vT, const __bf16* __restrict__ Pt,
    float* __restrict__ out)
{
    __shared__ __align__(16) __bf16 As[128][64];
    __shared__ __align__(16) __bf16 Bs[128][64];

    const int t  = blockIdx.x;
    const int n0 = blockIdx.y * 128;

    const int tid  = threadIdx.x;
    const int wave = tid >> 6, lane = tid & 63;
    const int fr = lane & 15, fq = lane >> 4;
    const int wr = (wave >> 1) * 64, wc = (wave & 1) * 64;
    const int lr = lane >> 3;
    const int cd = (lane & 7) ^ lr;
    const int srow = wave * 32 + lr;

    f32x4 acc[4][4];
#pragma unroll
    for (int a = 0; a < 4; ++a)
#pragma unroll
        for (int b = 0; b < 4; ++b) acc[a][b] = f32x4{0.f, 0.f, 0.f, 0.f};

    __bf16* al = &As[wave * 32][0];
    __bf16* bl = &Bs[wave * 32][0];

    // ---- Phase B: inter, acc = q_t @ Pt_t, K=512 ----
    if (t > 0) {
        const __bf16* ag = q + (size_t)(t * 128 + srow) * 512 + cd * 8;
        const __bf16* bg2 = Pt + (size_t)t * 262144
                          + (size_t)(n0 + srow) * 512 + cd * 8;
        for (int kk = 0; kk < 512; kk += 64) {
            __syncthreads();
#pragma unroll
            for (int u = 0; u < 4; ++u) {
                ld16(ag + (size_t)(u * 8) * 512 + kk, al + u * 512);
                ld16(bg2 + (size_t)(u * 8) * 512 + kk, bl + u * 512);
            }
            __syncthreads();
#pragma unroll
            for (int ks = 0; ks < 2; ++ks) {
                bf16x8 af[4], bf[4];
#pragma unroll
                for (int rt = 0; rt < 4; ++rt)
                    af[rt] = frag(&As[0][0], wr + rt * 16 + fr, ks * 4 + fq);
#pragma unroll
                for (int nt = 0; nt < 4; ++nt)
                    bf[nt] = frag(&Bs[0][0], wc + nt * 16 + fr, ks * 4 + fq);
#pragma unroll
                for (int rt = 0; rt < 4; ++rt)
#pragma unroll
                    for (int nt = 0; nt < 4; ++nt)
                        acc[rt][nt] = MFMA16(af[rt], bf[nt], acc[rt][nt]);
            }
        }
    }

    // ---- Phase C: acc += Sd[t] @ v_t, K=128 (both staged via ld16) ----
    const __bf16* at3 = Sd + (size_t)t * 16384 + (size_t)srow * 128 + cd * 8;
    const __bf16* bg3 = vT + (size_t)(n0 + srow) * 8192 + t * 128 + cd * 8;
    for (int kk = 0; kk < 128; kk += 64) {
        __syncthreads();
#pragma unroll
        for (int u = 0; u < 4; ++u) {
            ld16(at3 + (size_t)(u * 8) * 128 + kk, al + u * 512);
            ld16(bg3 + (size_t)(u * 8) * 8192 + kk, bl + u * 512);
        }
        __syncthreads();
#pragma unroll
        for (int ks = 0; ks < 2; ++ks) {
            bf16x8 af[4], bf[4];
#pragma unroll
            for (int rt = 0; rt < 4; ++rt)
                af[rt] = frag(&As[0][0], wr + rt * 16 + fr, ks * 4 + fq);
#pragma unroll
            for (int nt = 0; nt < 4; ++nt)
                bf[nt] = frag(&Bs[0][0], wc + nt * 16 + fr, ks * 4 + fq);
#pragma unroll
            for (int rt = 0; rt < 4; ++rt)
#pragma unroll
                for (int nt = 0; nt < 4; ++nt)
                    acc[rt][nt] = MFMA16(af[rt], bf[nt], acc[rt][nt]);
        }
    }

    // epilogue: exclusive owner of this 128x128 tile -> plain fp32 store
#pragma unroll
    for (int rt = 0; rt < 4; ++rt)
#pragma unroll
        for (int nt = 0; nt < 4; ++nt) {
            const int col = n0 + wc + nt * 16 + fr;
#pragma unroll
            for (int r = 0; r < 4; ++r) {
                const int row = t * 128 + wr + rt * 16 + fq * 4 + r;
                out[(size_t)row * 512 + col] = acc[rt][nt][r];
            }
        }
}

// ---------------------------------------------------------------------------
extern "C" void kernel_launch(void* const* d_in, const int* in_sizes, int n_in,
                              void* d_out, int out_size, void* d_ws, size_t ws_size,
                              hipStream_t stream) {
    const float* x  = (const float*)d_in[0];
    const float* y  = (const float*)d_in[1];
    const float* Wq = (const float*)d_in[2];
    const float* Wk = (const float*)d_in[3];
    const float* Wv = (const float*)d_in[4];
    float* out = (float*)d_out;

    const size_t QK = (size_t)8192 * 512;       // 4194304
    __bf16* q  = (__bf16*)d_ws;
    __bf16* k  = q + QK;
    __bf16* kT = k + QK;
    __bf16* vT = kT + QK;
    __bf16* Ht  = vT + QK;                      // 16777216-elem region
    __bf16* Pt  = Ht + 16777216;                // 16777216-elem region
    __bf16* wqb = Pt + 16777216;
    __bf16* wkb = wqb + 1048576;
    __bf16* wvb = wkb + 1048576;
    __bf16* Sd = wqb;                           // alias: wqb dead after gemm

    convert_w<<<1536, 256, 0, stream>>>(Wq, Wk, Wv, wqb, wkb, wvb);
    gemm_qkv2<<<dim3(64, 8), 256, 0, stream>>>(x, y, wqb, wkb, wvb, q, k, kT, vT);
    hs_gemm<<<dim3(16, 67), 256, 0, stream>>>(vT, kT, q, k, Ht, Sd);
    prefix_scan<<<512, 256, 0, stream>>>(Ht, Pt);
    out_gemm<<<dim3(64, 4), 256, 0, stream>>>(q, Sd, vT, Pt, out);
}